// Round 6
// baseline (803.015 us; speedup 1.0000x reference)
//
#include <hip/hip_runtime.h>

typedef unsigned short u16;
typedef __bf16 bf16x8 __attribute__((ext_vector_type(8)));
typedef unsigned short ushort8 __attribute__((ext_vector_type(8)));
typedef float f32x4 __attribute__((ext_vector_type(4)));

typedef const __attribute__((address_space(1))) void gv_t;  // global
typedef __attribute__((address_space(3))) void lv_t;        // LDS

__device__ __forceinline__ u16 f2bf(float f) {
    union { float f; unsigned u; } x; x.f = f;
    unsigned r = x.u + 0x7fffu + ((x.u >> 16) & 1u);
    return (u16)(r >> 16);
}
__device__ __forceinline__ float bf2f(u16 h) {
    union { unsigned u; float f; } x; x.u = ((unsigned)h) << 16; return x.f;
}
__device__ __forceinline__ bf16x8 as_bf(ushort8 u) {
    union { ushort8 u; bf16x8 b; } x; x.u = u; return x.b;
}

// ------------- k_prep: all casts + transposes in ONE launch -------------
// jobs (1D grid, 28928 blocks of (32,8)):
//   [0,2048)      cast midq -> midqh   (f32->bf16, contiguous)
//   [2048,4096)   cast midk -> midkh
//   [4096,8192)   W1   [2048,2048] -> W1t   (transpose, 64x64 tiles)
//   [8192,24576)  Wlin [2048,8192] -> WlinT (256x64 tiles)
//   [24576,24832) W2   [2048,128]  -> W2t   (4x64 tiles)
//   [24832,28928) nq   [128,32768] -> nqT   (1024x4 tiles)
__global__ void k_prep(const float* __restrict__ midq, const float* __restrict__ midk,
                       u16* __restrict__ midqh, u16* __restrict__ midkh,
                       const float* __restrict__ W1, u16* __restrict__ W1t,
                       const float* __restrict__ Wlin, u16* __restrict__ WlinT,
                       const float* __restrict__ W2, u16* __restrict__ W2t,
                       const float* __restrict__ nq, u16* __restrict__ nqT) {
    int bid = blockIdx.x;
    int t = threadIdx.y * 32 + threadIdx.x;
    if (bid < 4096) {  // contiguous casts: 2048 blocks x 256 threads x float4
        const float* in = (bid < 2048) ? midq : midk;
        u16* outp = (bid < 2048) ? midqh : midkh;
        long i = (long)(bid & 2047) * 256 + t;
        float4 v = ((const float4*)in)[i];
        u16 o[4] = {f2bf(v.x), f2bf(v.y), f2bf(v.z), f2bf(v.w)};
        *(unsigned long long*)(outp + i * 4) = *(unsigned long long*)o;
        return;
    }
    int b = bid - 4096;
    const float* in; u16* outp; int R, C, ctiles;
    if (b < 4096)       { in = W1;   outp = W1t;   R = 2048; C = 2048;  ctiles = 64; }
    else if (b < 20480) { b -= 4096;  in = Wlin; outp = WlinT; R = 2048; C = 8192;  ctiles = 256; }
    else if (b < 20736) { b -= 20480; in = W2;   outp = W2t;   R = 2048; C = 128;   ctiles = 4; }
    else                { b -= 20736; in = nq;   outp = nqT;   R = 128;  C = 32768; ctiles = 1024; }
    int c0 = (b % ctiles) * 32, r0 = (b / ctiles) * 32;
    __shared__ u16 tile[32][33];
    int tx = threadIdx.x, ty = threadIdx.y;
#pragma unroll
    for (int i = 0; i < 4; i++)
        tile[ty + 8 * i][tx] = f2bf(in[(size_t)(r0 + ty + 8 * i) * C + c0 + tx]);
    __syncthreads();
#pragma unroll
    for (int i = 0; i < 4; i++)
        outp[(size_t)(c0 + ty + 8 * i) * R + r0 + tx] = tile[tx][ty + 8 * i];
}

// ---------------- GEMM: C[M,N] = A[M,K] @ Bt[N,K]^T ----------------
// m97 structure: BK=32, linear LDS [128][32], async global->LDS DMA (16B/lane).
// EPI 2: split-K partial store to Cs[kc][1024][ldc] (F = G @ W2).
// EPI 4: merged H+logits, B = contiguous [W1t|WlinT] (ldb 2048). by<16 -> H
//        bf16 (+b1) AND fused bn_stats (column sum/sumsq -> atomicAdd ps/ps2,
//        pre-ReLU as reference requires); by>=16 -> logits f32 (+blin).
//        XCD-bijective swizzle: each XCD owns a 10-tile B-band (L2 residency).
// EPI 5: merged sim_batch+neg_list (K=128) + fused labels_con stores:
//        by<8 -> sim value + (lq==lk) label; by>=8 -> neg remap value + 0 label.
template <int EPI>
__global__ __launch_bounds__(256, 2) void gemm_bt(
    const u16* A0, const u16* A1, const u16* __restrict__ Bt,
    const u16* __restrict__ Bt2, const float* __restrict__ bias,
    const float* __restrict__ bias2, u16* H0, u16* H1, float* C0, float* C1,
    int lda, int ldb, long long ldc, int n_tiles, int Kchunk,
    const int* __restrict__ labels, const int* __restrict__ labelsK,
    float* outL, float* psA, float* ps2A) {
    __shared__ u16 Al[128 * 32];
    __shared__ u16 Bl[128 * 32];

    int bx, by, kc, half;
    if (EPI == 4) {
        // grid (8,80,2) -> 1280 blocks. XCD x gets by-band [x*10, x*10+10).
        int pid = blockIdx.x + blockIdx.y * 8 + blockIdx.z * 640;
        int xcd = pid & 7, idx = pid >> 3;   // idx 0..159
        by = xcd * 10 + idx % 10;
        int rem = idx / 10;                  // 0..15
        bx = rem & 7; half = rem >> 3; kc = 0;
    } else if (EPI == 5) {
        bx = blockIdx.x; by = blockIdx.y; kc = 0; half = 0;
    } else {
        bx = blockIdx.x; by = blockIdx.y % n_tiles; kc = blockIdx.y / n_tiles;
        half = blockIdx.z;
    }
    const u16* A = half ? A1 : A0;

    const u16* B = Bt;
    int bn0 = by * 128;
    if (EPI == 5 && by >= 8) { B = Bt2; bn0 = (by - 8) * 128; }

    const int m0 = bx * 128;
    const int t = threadIdx.x;
    const int w = t >> 6, l = t & 63;
    const int wm = (w & 1) * 64, wn = (w >> 1) * 64;
    const int quad = l >> 4, ln = l & 15;
    const int srow = t >> 2;        // 0..63 (row within 64-row half-panel)
    const int sk = (t & 3) * 8;     // k-chunk within 32

    f32x4 acc[4][4];
#pragma unroll
    for (int i = 0; i < 4; i++)
#pragma unroll
        for (int j = 0; j < 4; j++) acc[i][j] = f32x4{};

    // wave-uniform LDS bases for staging (16 rows x 32 u16 = 1024 B per wave)
    u16* lAw = Al + (w << 4) * 32;
    u16* lBw = Bl + (w << 4) * 32;

    const int k_begin = kc * Kchunk;
    for (int k0 = k_begin; k0 < k_begin + Kchunk; k0 += 32) {
        if (k0 != k_begin) __syncthreads();  // readers of previous tile done
#pragma unroll
        for (int i = 0; i < 2; i++) {
            __builtin_amdgcn_global_load_lds(
                (gv_t*)(A + (size_t)(m0 + srow + i * 64) * lda + k0 + sk),
                (lv_t*)(lAw + i * 64 * 32), 16, 0, 0);
            __builtin_amdgcn_global_load_lds(
                (gv_t*)(B + (size_t)(bn0 + srow + i * 64) * ldb + k0 + sk),
                (lv_t*)(lBw + i * 64 * 32), 16, 0, 0);
        }
        __syncthreads();  // drains vmcnt(0): staged tile visible to all waves
        bf16x8 af[4], bb[4];
#pragma unroll
        for (int i = 0; i < 4; i++) {
            af[i] = as_bf(*(const ushort8*)(Al + (wm + i * 16 + ln) * 32 + quad * 8));
            bb[i] = as_bf(*(const ushort8*)(Bl + (wn + i * 16 + ln) * 32 + quad * 8));
        }
#pragma unroll
        for (int i = 0; i < 4; i++)
#pragma unroll
            for (int j = 0; j < 4; j++)
                acc[i][j] = __builtin_amdgcn_mfma_f32_16x16x32_bf16(af[i], bb[j], acc[i][j], 0, 0, 0);
    }

    if (EPI == 2) {
        float* Cs = half ? C1 : C0;
#pragma unroll
        for (int i = 0; i < 4; i++) {
            int row = m0 + wm + i * 16 + quad * 4;
#pragma unroll
            for (int j = 0; j < 4; j++) {
                int col = by * 128 + wn + j * 16 + ln;
#pragma unroll
                for (int r = 0; r < 4; r++)
                    Cs[(size_t)kc * (1024 * (size_t)ldc) + (size_t)(row + r) * ldc + col] = acc[i][j][r];
            }
        }
    } else if (EPI == 4) {
        if (by < 16) {       // H half: bf16 + b1, fused bn_stats (pre-ReLU)
            u16* Hs = half ? H1 : H0;
            float* psb = psA + half * 2048;
            float* ps2b = ps2A + half * 2048;
#pragma unroll
            for (int j = 0; j < 4; j++) {
                int col = by * 128 + wn + j * 16 + ln;
                float bv = bias[col];
                float sj = 0.f, s2j = 0.f;
#pragma unroll
                for (int i = 0; i < 4; i++) {
                    int row = m0 + wm + i * 16 + quad * 4;
#pragma unroll
                    for (int r = 0; r < 4; r++) {
                        float v = acc[i][j][r] + bv;
                        Hs[(size_t)(row + r) * 2048 + col] = f2bf(v);
                        sj += v; s2j += v * v;
                    }
                }
                // combine the 4 quad-lanes holding the same column (16 rows each)
                sj += __shfl_xor(sj, 16); sj += __shfl_xor(sj, 32);
                s2j += __shfl_xor(s2j, 16); s2j += __shfl_xor(s2j, 32);
                if (quad == 0) { atomicAdd(psb + col, sj); atomicAdd(ps2b + col, s2j); }
            }
        } else {             // logits: f32 + blin
            float* Cs = half ? C1 : C0;
#pragma unroll
            for (int j = 0; j < 4; j++) {
                int col = (by - 16) * 128 + wn + j * 16 + ln;
                float bv = bias2[col];
#pragma unroll
                for (int i = 0; i < 4; i++) {
                    int row = m0 + wm + i * 16 + quad * 4;
#pragma unroll
                    for (int r = 0; r < 4; r++)
                        Cs[(size_t)(row + r) * 8192 + col] = acc[i][j][r] + bv;
                }
            }
        }
    } else if (EPI == 5) {
        if (by < 8) {        // sim_batch cols [0,1024) + labels_batch
#pragma unroll
            for (int j = 0; j < 4; j++) {
                int col = by * 128 + wn + j * 16 + ln;
                int lblc = labelsK[col];
#pragma unroll
                for (int i = 0; i < 4; i++) {
                    int row = m0 + wm + i * 16 + quad * 4;
#pragma unroll
                    for (int r = 0; r < 4; r++) {
                        int rr = row + r;
                        C0[(size_t)rr * 33796 + col] = acc[i][j][r];
                        outL[(size_t)rr * 33796 + col] = (labels[rr] == lblc) ? 1.f : 0.f;
                    }
                }
            }
        } else {             // neg-list remap (skip own-class) + zero labels
#pragma unroll
            for (int j = 0; j < 4; j++) {
                int col = (by - 8) * 128 + wn + j * 16 + ln;
#pragma unroll
                for (int i = 0; i < 4; i++) {
                    int row = m0 + wm + i * 16 + quad * 4;
#pragma unroll
                    for (int r = 0; r < 4; r++) {
                        int rr = row + r;
                        int L4 = labels[rr] * 4;
                        if (col < L4 || col >= L4 + 4) {
                            size_t dst = (size_t)rr * 33796 + 1032 + col - (col >= L4 + 4 ? 4 : 0);
                            C0[dst] = acc[i][j][r];
                            outL[dst] = 0.f;
                        }
                    }
                }
            }
        }
    }
}

// ---------------- BN final: ps/ps2 are atomically-accumulated sums ----------
__global__ void k_bn_final(const float* __restrict__ ps, const float* __restrict__ ps2,
                           const float* __restrict__ gamma, const float* __restrict__ beta,
                           float* __restrict__ scale, float* __restrict__ shift) {
    int idx = blockIdx.x * 256 + threadIdx.x;  // 0..4095
    int half = idx >> 11, col = idx & 2047;
    float s = ps[half * 2048 + col];
    float s2 = ps2[half * 2048 + col];
    float mu = s * (1.f / 1024.f);
    float var = s2 * (1.f / 1024.f) - mu * mu;
    float sc = gamma[col] * rsqrtf(var + 1e-5f);
    shift[half * 2048 + col] = beta[col] - mu * sc;
    scale[half * 2048 + col] = sc;
}

__global__ void k_bn_apply(u16* Hq, u16* Hk, const float* __restrict__ scale,
                           const float* __restrict__ shift) {
    int row = blockIdx.x, half = blockIdx.y;
    u16* H = half ? Hk : Hq;
    int col = threadIdx.x * 8;
    ushort8 h = *(ushort8*)(H + (size_t)row * 2048 + col);
    ushort8 o;
#pragma unroll
    for (int k = 0; k < 8; k++) {
        float v = bf2f(h[k]) * scale[half * 2048 + col + k] + shift[half * 2048 + col + k];
        o[k] = f2bf(fmaxf(v, 0.f));
    }
    *(ushort8*)(H + (size_t)row * 2048 + col) = o;
}

// ---------------- L2 norm rows (+b2) over split-K partials; fused pos_list
// and labels_con "ones" at cols [1024,1032) ----
__global__ void k_l2norm(const float* __restrict__ Fqp, const float* __restrict__ Fkp,
                         const float* __restrict__ b2, float* fqf, float* fkf,
                         u16* fqh, u16* fkh, const float* __restrict__ pq,
                         const int* __restrict__ lq, float* __restrict__ out0,
                         float* __restrict__ out1) {
    int row = blockIdx.x, half = blockIdx.y, d = threadIdx.x;
    const float* Fp = half ? Fkp : Fqp;
    float x = b2[d];
#pragma unroll
    for (int kc = 0; kc < 8; kc++)
        x += Fp[(size_t)kc * 131072 + (size_t)row * 128 + d];
    float ss = x * x;
#pragma unroll
    for (int off = 32; off >= 1; off >>= 1) ss += __shfl_down(ss, off);
    __shared__ float p[2];
    if ((threadIdx.x & 63) == 0) p[threadIdx.x >> 6] = ss;
    __syncthreads();
    float n = sqrtf(p[0] + p[1]);
    float v = x / fmaxf(n, 1e-12f);
    (half ? fkf : fqf)[(size_t)row * 128 + d] = v;
    (half ? fkh : fqh)[(size_t)row * 128 + d] = f2bf(v);

    if (half == 0) {  // block-uniform branch: fused pos_list + label ones
        int base = lq[row] * 8;
        const float* pp = pq + (size_t)d * 65536 + base;
        float4 v0 = *(const float4*)pp;
        float4 v1 = *(const float4*)(pp + 4);
        float a[8] = {v * v0.x, v * v0.y, v * v0.z, v * v0.w,
                      v * v1.x, v * v1.y, v * v1.z, v * v1.w};
#pragma unroll
        for (int off = 32; off >= 1; off >>= 1)
#pragma unroll
            for (int q = 0; q < 8; q++) a[q] += __shfl_down(a[q], off);
        __shared__ float pr[2][8];
        if ((threadIdx.x & 63) == 0) {
#pragma unroll
            for (int q = 0; q < 8; q++) pr[threadIdx.x >> 6][q] = a[q];
        }
        __syncthreads();
        if (threadIdx.x < 8) {
            out0[(size_t)row * 33796 + 1024 + threadIdx.x] =
                pr[0][threadIdx.x] + pr[1][threadIdx.x];
            out1[(size_t)row * 33796 + 1024 + threadIdx.x] = 1.f;
        }
    }
}

// ---------------- two f32 vector copies in one launch ----------------
__global__ void k_copy2(const float* __restrict__ s1, float* __restrict__ d1, long n1,
                        const float* __restrict__ s2, float* __restrict__ d2, long n2) {
    long i = (long)blockIdx.x * blockDim.x + threadIdx.x;
    long stride = (long)gridDim.x * blockDim.x;
    long tot = n1 + n2;
    for (; i < tot; i += stride) {
        if (i < n1) ((float4*)d1)[i] = ((const float4*)s1)[i];
        else ((float4*)d2)[i - n1] = ((const float4*)s2)[i - n1];
    }
}

// ---------------- queue bookkeeping (8-way parallel rank) ----------------
__global__ void k_rank(const int* __restrict__ lk, const int* __restrict__ nptr,
                       const int* __restrict__ pptr, int* __restrict__ counts,
                       int* __restrict__ colN, int* __restrict__ colP) {
    __shared__ int lab[1024];
    int tid = threadIdx.x;  // 128 threads
    for (int i = tid; i < 1024; i += 128) lab[i] = lk[i];
    __syncthreads();
    int b = blockIdx.x * 128 + tid;
    int c = lab[b];
    int rank = 0, count = 0;
    for (int i = 0; i < 1024; i++) {
        int m = (lab[i] == c);
        count += m;
        rank += (i < b) ? m : 0;
    }
    if (rank == count - 1) counts[c] = count;
    colN[b] = (rank >= count - 4) ? c * 4 + (nptr[c] + rank) % 4 : -1;
    colP[b] = (rank >= count - 8) ? c * 8 + (pptr[c] + rank) % 8 : -1;
}

// scatter (blocks 0..511, 2 rows each) + ptr outputs (blocks 512..543)
__global__ void k_scatter_ptrs(const float* __restrict__ fkf,
                               const int* __restrict__ colN, const int* __restrict__ colP,
                               const int* __restrict__ nptr, const int* __restrict__ pptr,
                               const int* __restrict__ counts,
                               float* outN, float* outP, float* outNp, float* outPp) {
    int bid = blockIdx.x;
    if (bid < 512) {
        int b = bid * 2 + (threadIdx.x >> 7);
        int d = threadIdx.x & 127;
        float v = fkf[(size_t)b * 128 + d];
        int cn = colN[b];
        if (cn >= 0) outN[(size_t)d * 32768 + cn] = v;
        int cp = colP[b];
        if (cp >= 0) outP[(size_t)d * 65536 + cp] = v;
    } else {
        int c = (bid - 512) * 256 + threadIdx.x;
        int cnt = counts[c];
        outNp[c] = (float)((nptr[c] + cnt) & 3);
        outPp[c] = (float)((pptr[c] + cnt) & 7);
    }
}

// ---------------- host ----------------
extern "C" void kernel_launch(void* const* d_in, const int* in_sizes, int n_in,
                              void* d_out, int out_size, void* d_ws, size_t ws_size,
                              hipStream_t stream) {
    const float* midq = (const float*)d_in[0];
    const float* midk = (const float*)d_in[1];
    const int* lq     = (const int*)d_in[2];
    const int* lk     = (const int*)d_in[3];
    const float* W1   = (const float*)d_in[4];
    const float* b1   = (const float*)d_in[5];
    const float* gamma= (const float*)d_in[6];
    const float* beta = (const float*)d_in[7];
    const float* W2   = (const float*)d_in[8];
    const float* b2   = (const float*)d_in[9];
    const float* Wlin = (const float*)d_in[10];
    const float* blin = (const float*)d_in[11];
    const float* nq   = (const float*)d_in[12];
    const float* pq   = (const float*)d_in[13];
    const int* nptr   = (const int*)d_in[14];
    const int* pptr   = (const int*)d_in[15];
    (void)in_sizes; (void)n_in; (void)out_size; (void)ws_size;

    float* out = (float*)d_out;
    const size_t O0 = 0;
    const size_t O1 = 34607104;   // labels_con
    const size_t O2 = 69214208;   // logit_q
    const size_t O3 = 77602816;   // logit_k
    const size_t O4 = 85991424;   // neg_queue2
    const size_t O5 = 90185728;   // pos_queue2
    const size_t O6 = 98574336;   // neg_ptr2
    const size_t O7 = 98582528;   // pos_ptr2

    char* ws = (char*)d_ws;
    size_t off = 0;
    auto alloc = [&](size_t bytes) -> char* {
        char* p = ws + off;
        off = (off + bytes + 255) & ~(size_t)255;
        return p;
    };
    // NOTE: W1t and WlinT MUST stay adjacent (contiguous [10240][2048] concat
    // for the merged H+logits GEMM). ps and ps2 MUST stay adjacent (one memset).
    u16* W1t   = (u16*)alloc((size_t)2048 * 2048 * 2);
    u16* WlinT = (u16*)alloc((size_t)8192 * 2048 * 2);
    u16* W2t   = (u16*)alloc((size_t)128 * 2048 * 2);
    u16* nqT   = (u16*)alloc((size_t)32768 * 128 * 2);
    u16* midqh = (u16*)alloc((size_t)1024 * 2048 * 2);
    u16* midkh = (u16*)alloc((size_t)1024 * 2048 * 2);
    u16* Hq    = (u16*)alloc((size_t)1024 * 2048 * 2);
    u16* Hk    = (u16*)alloc((size_t)1024 * 2048 * 2);
    float* Fq  = (float*)alloc((size_t)8 * 1024 * 128 * 4);  // split-K partials
    float* Fk  = (float*)alloc((size_t)8 * 1024 * 128 * 4);
    float* fqf = (float*)alloc((size_t)1024 * 128 * 4);
    float* fkf = (float*)alloc((size_t)1024 * 128 * 4);
    u16* fqh   = (u16*)alloc((size_t)1024 * 128 * 2);
    u16* fkh   = (u16*)alloc((size_t)1024 * 128 * 2);
    float* ps  = (float*)alloc((size_t)2 * 2048 * 4);   // atomic col sums
    float* ps2 = (float*)alloc((size_t)2 * 2048 * 4);   // atomic col sumsq
    float* scaleA = (float*)alloc((size_t)2 * 2048 * 4);
    float* shiftA = (float*)alloc((size_t)2 * 2048 * 4);
    int* counts = (int*)alloc(8192 * 4);
    int* colN   = (int*)alloc(1024 * 4);
    int* colP   = (int*)alloc(1024 * 4);

    hipMemsetAsync(ps, 0, 2 * 2 * 2048 * 4, stream);  // ps + ps2 (adjacent)
    hipMemsetAsync(counts, 0, 8192 * 4, stream);

    // all casts/transposes in one launch
    k_prep<<<28928, dim3(32, 8), 0, stream>>>(midq, midk, midqh, midkh,
        W1, W1t, Wlin, WlinT, W2, W2t, nq, nqT);

    // merged: H = X@W1+b1 (bf16, tiles 0..15, fused bn_stats) and
    // logits = X@Wlin+blin (f32, tiles 16..79); B = contiguous [W1t|WlinT]
    gemm_bt<4><<<dim3(8, 80, 2), 256, 0, stream>>>(midqh, midkh, W1t, nullptr,
        b1, blin, Hq, Hk, out + O2, out + O3, 2048, 2048, 0, 80, 2048,
        nullptr, nullptr, nullptr, ps, ps2);

    k_bn_final<<<16, 256, 0, stream>>>(ps, ps2, gamma, beta, scaleA, shiftA);
    k_bn_apply<<<dim3(1024, 2), 256, 0, stream>>>(Hq, Hk, scaleA, shiftA);

    // F = G @ W2 (split-K=8, partial stores; reduced in k_l2norm)
    gemm_bt<2><<<dim3(8, 8, 2), 256, 0, stream>>>(Hq, Hk, W2t, nullptr, nullptr,
        nullptr, nullptr, nullptr, Fq, Fk, 2048, 2048, 128, 1, 256,
        nullptr, nullptr, nullptr, nullptr, nullptr);

    k_l2norm<<<dim3(1024, 2), 128, 0, stream>>>(Fq, Fk, b2, fqf, fkf, fqh, fkh,
                                                pq, lq, out + O0, out + O1);

    // merged: sim_batch (tiles 0..7) + neg_list (tiles 8..263), with fused
    // labels_con stores (labels_batch / zeros)
    gemm_bt<5><<<dim3(8, 264, 1), 256, 0, stream>>>(fqh, fqh, fkh, nqT,
        nullptr, nullptr, nullptr, nullptr, out + O0, out + O0,
        128, 128, 33796, 264, 128, lq, lk, out + O1, nullptr, nullptr);

    k_copy2<<<2048, 256, 0, stream>>>(nq, out + O4, 4194304 / 4,
                                      pq, out + O5, 8388608 / 4);

    k_rank<<<8, 128, 0, stream>>>(lk, nptr, pptr, counts, colN, colP);
    k_scatter_ptrs<<<544, 256, 0, stream>>>(fkf, colN, colP, nptr, pptr, counts,
                                            out + O4, out + O5, out + O6, out + O7);
}